// Round 2
// baseline (11366.068 us; speedup 1.0000x reference)
//
#include <hip/hip_runtime.h>
#include <stdint.h>

// T=1024, B=32, D=H=1024.  M = T*B = 32768.
typedef float  f32x4  __attribute__((ext_vector_type(4)));
typedef short  bf16x8 __attribute__((ext_vector_type(8)));

__device__ __forceinline__ unsigned short f2bf(float f) {
  union { float f; unsigned u; } v; v.f = f;
  unsigned r = v.u + 0x7fffu + ((v.u >> 16) & 1u);   // RNE, inputs are finite
  return (unsigned short)(r >> 16);
}
__device__ __forceinline__ float bf2f(unsigned short s) {
  union { unsigned u; float f; } v; v.u = ((unsigned)s) << 16; return v.f;
}
__device__ __forceinline__ bf16x8 pack8(float4 a, float4 b) {
  bf16x8 v;
  v[0]=(short)f2bf(a.x); v[1]=(short)f2bf(a.y); v[2]=(short)f2bf(a.z); v[3]=(short)f2bf(a.w);
  v[4]=(short)f2bf(b.x); v[5]=(short)f2bf(b.y); v[6]=(short)f2bf(b.z); v[7]=(short)f2bf(b.w);
  return v;
}
__device__ __forceinline__ unsigned long long pack4bf(float a, float b, float c, float d) {
  return (unsigned long long)f2bf(a) | ((unsigned long long)f2bf(b) << 16)
       | ((unsigned long long)f2bf(c) << 32) | ((unsigned long long)f2bf(d) << 48);
}
__device__ __forceinline__ f32x4 mfma16(bf16x8 a, bf16x8 b, f32x4 c) {
  return __builtin_amdgcn_mfma_f32_16x16x32_bf16(a, b, c, 0, 0, 0);
}
// fast tanh: 1 - 2/(exp(2y)+1); v_exp/v_rcp are ~1ulp, saturates correctly.
__device__ __forceinline__ float fast_tanh(float y) {
  return 1.0f - 2.0f * __builtin_amdgcn_rcpf(__expf(2.0f * y) + 1.0f);
}

// ---------------------------------------------------------------------------
// Phase 1 (unchanged, known-good): wx = x@Wx^T + bias -> d_out (fp32);
// delta = sigmoid(x@Wd^T + b_delta) -> ws (bf16).
// ---------------------------------------------------------------------------
__global__ __launch_bounds__(256) void proj_kernel(
    const float* __restrict__ x,  const float* __restrict__ Wx,
    const float* __restrict__ Wd, const float* __restrict__ bias,
    const float* __restrict__ bd, float* __restrict__ wx_out,
    unsigned short* __restrict__ delta_out)
{
  __shared__ __align__(16) unsigned short lA[128 * 40];
  __shared__ __align__(16) unsigned short lB[128 * 40];

  const int tid  = threadIdx.x;
  const int lane = tid & 63;
  const int wv   = tid >> 6;
  const int wm   = (wv >> 1) * 64;
  const int wn   = (wv & 1) * 64;
  const int l15  = lane & 15, lhi = lane >> 4;

  const int  bm    = blockIdx.x;
  const int  bn    = blockIdx.y;
  const bool isd   = bn >= 8;
  const float* W   = isd ? Wd : Wx;
  const int  ncol0 = (bn & 7) * 128;
  const int  row0  = bm * 128;

  const int srow = tid >> 1;
  const int scol = (tid & 1) * 16;

  f32x4 acc[4][4] = {};

  for (int k0 = 0; k0 < 1024; k0 += 32) {
    const float* pa = x + (size_t)(row0 + srow) * 1024 + (k0 + scol);
    const float* pb = W + (size_t)(ncol0 + srow) * 1024 + (k0 + scol);
    float4 a0 = *(const float4*)(pa + 0), a1 = *(const float4*)(pa + 4);
    float4 a2 = *(const float4*)(pa + 8), a3 = *(const float4*)(pa + 12);
    float4 b0 = *(const float4*)(pb + 0), b1 = *(const float4*)(pb + 4);
    float4 b2 = *(const float4*)(pb + 8), b3 = *(const float4*)(pb + 12);

    *(bf16x8*)&lA[srow * 40 + scol]     = pack8(a0, a1);
    *(bf16x8*)&lA[srow * 40 + scol + 8] = pack8(a2, a3);
    *(bf16x8*)&lB[srow * 40 + scol]     = pack8(b0, b1);
    *(bf16x8*)&lB[srow * 40 + scol + 8] = pack8(b2, b3);
    __syncthreads();

    bf16x8 af[4], bfr[4];
    #pragma unroll
    for (int i = 0; i < 4; ++i) {
      af[i]  = *(const bf16x8*)&lA[(wm + i * 16 + l15) * 40 + lhi * 8];
      bfr[i] = *(const bf16x8*)&lB[(wn + i * 16 + l15) * 40 + lhi * 8];
    }
    #pragma unroll
    for (int i = 0; i < 4; ++i)
      #pragma unroll
      for (int j = 0; j < 4; ++j)
        acc[i][j] = mfma16(af[i], bfr[j], acc[i][j]);
    __syncthreads();
  }

  #pragma unroll
  for (int i = 0; i < 4; ++i) {
    const int rbase = row0 + wm + i * 16 + lhi * 4;
    #pragma unroll
    for (int j = 0; j < 4; ++j) {
      const int col = ncol0 + wn + j * 16 + l15;
      #pragma unroll
      for (int r = 0; r < 4; ++r) {
        const size_t idx = (size_t)(rbase + r) * 1024 + col;
        const float v = acc[i][j][r];
        if (!isd) {
          wx_out[idx] = v + bias[col];
        } else {
          const float s = 1.0f / (1.0f + expf(-(v + bd[col])));
          delta_out[idx] = f2bf(s);
        }
      }
    }
  }
}

// ---------------------------------------------------------------------------
// Phase 2: persistent recurrence, fence-free coherent h-exchange.
// grid = 16 WGs x 256 thr: blockIdx = bg*8 + chunk (bg = batch group of 16).
// Transposed MFMA: y^T = R @ h^T.  R = A-operand (reg-resident, ra[2][32]),
// h = B-operand loaded per step via agent-scope (L2-bypassing) 8B atomic
// loads.  C layout => lane owns 4 CONSECUTIVE h-columns of one batch:
// publish = 2 packed 8B agent atomic stores; out = 2 float4 stores.
// Flag protocol: stores -> __syncthreads (implies per-thread vmcnt(0)) ->
// tid0 atomicAdd; consumer spins on relaxed agent load.  No threadfence,
// so no L2 writeback/invalidate on the critical path.
// ---------------------------------------------------------------------------
__global__ __launch_bounds__(256, 1) void rnn_kernel(
    const float* __restrict__ R, const float* __restrict__ h0,
    float* __restrict__ out, const unsigned short* __restrict__ delta,
    unsigned short* __restrict__ hbuf, unsigned int* __restrict__ counters)
{
  const int tid  = threadIdx.x;
  const int lane = tid & 63;
  const int wv   = tid >> 6;
  const int l15  = lane & 15, lhi = lane >> 4;
  const int chunk = blockIdx.x & 7;
  const int bg    = blockIdx.x >> 3;
  const int B0    = bg * 16;
  const int cb    = chunk * 128 + wv * 32;
  unsigned int* cnt = counters + bg * 16;   // 64 B apart

  // R fragments as A-operand: ra[nt][kt] = R[j=cb+nt*16+l15][kt*32+lhi*8 ..+7]
  bf16x8 ra[2][32];
  #pragma unroll
  for (int nt = 0; nt < 2; ++nt) {
    const float* rrow = R + (size_t)(cb + nt * 16 + l15) * 1024 + lhi * 8;
    #pragma unroll
    for (int kt = 0; kt < 32; ++kt) {
      float4 u0 = *(const float4*)(rrow + kt * 32);
      float4 u1 = *(const float4*)(rrow + kt * 32 + 4);
      ra[nt][kt] = pack8(u0, u1);
    }
  }

  const int b = B0 + l15;                       // this lane's batch
  const int j0[2] = { cb + lhi * 4, cb + 16 + lhi * 4 };

  // init h + publish into parity-0 buffer
  float hloc[2][4];
  #pragma unroll
  for (int nt = 0; nt < 2; ++nt) {
    const f32x4 hv = *(const f32x4*)(h0 + (size_t)b * 1024 + j0[nt]);
    hloc[nt][0] = hv[0]; hloc[nt][1] = hv[1];
    hloc[nt][2] = hv[2]; hloc[nt][3] = hv[3];
    __hip_atomic_store((unsigned long long*)(hbuf + (size_t)b * 1024 + j0[nt]),
                       pack4bf(hv[0], hv[1], hv[2], hv[3]),
                       __ATOMIC_RELAXED, __HIP_MEMORY_SCOPE_AGENT);
  }
  __syncthreads();                               // all init stores vmcnt-drained
  if (tid == 0) atomicAdd(cnt, 1u);

  unsigned int target = 8;
  const size_t hbase = (size_t)b * 1024 + lhi * 8;   // halves, B-frag base

  for (int t = 0; t < 1024; ++t) {
    const unsigned short* hin  = hbuf + (t & 1) * 32768;
    unsigned short*       hout = hbuf + ((t & 1) ^ 1) * 32768;
    float*                outp = out + (size_t)t * 32768;
    const unsigned short* dp   = delta + (size_t)t * 32768;

    // Prefetch wx / delta (plain loads, overlap the spin below).
    f32x4 wx4[2]; unsigned long long d4[2];
    #pragma unroll
    for (int nt = 0; nt < 2; ++nt) {
      wx4[nt] = *(const f32x4*)(outp + (size_t)b * 1024 + j0[nt]);
      d4[nt]  = *(const unsigned long long*)(dp + (size_t)b * 1024 + j0[nt]);
    }

    // Wait for all 8 chunks of h_{t-1} in this batch group.
    if (tid == 0) {
      while (__hip_atomic_load(cnt, __ATOMIC_RELAXED, __HIP_MEMORY_SCOPE_AGENT) < target) {}
    }
    __syncthreads();

    // y^T = R_chunk @ h^T  (h via coherent 8B loads, 4-way split acc chains)
    f32x4 acc[2][4] = {};
    #pragma unroll
    for (int kt = 0; kt < 32; ++kt) {
      const unsigned long long lo = __hip_atomic_load(
          (const unsigned long long*)(hin + hbase + kt * 32),
          __ATOMIC_RELAXED, __HIP_MEMORY_SCOPE_AGENT);
      const unsigned long long hi = __hip_atomic_load(
          (const unsigned long long*)(hin + hbase + kt * 32 + 4),
          __ATOMIC_RELAXED, __HIP_MEMORY_SCOPE_AGENT);
      union { unsigned long long q[2]; bf16x8 v; } cvt;
      cvt.q[0] = lo; cvt.q[1] = hi;
      const bf16x8 a = cvt.v;
      acc[0][kt & 3] = mfma16(ra[0][kt], a, acc[0][kt & 3]);
      acc[1][kt & 3] = mfma16(ra[1][kt], a, acc[1][kt & 3]);
    }

    // blend + publish (publish first: gets the coherent stores in flight)
    #pragma unroll
    for (int nt = 0; nt < 2; ++nt) {
      const f32x4 y = (acc[nt][0] + acc[nt][1]) + (acc[nt][2] + acc[nt][3]) + wx4[nt];
      f32x4 o;
      #pragma unroll
      for (int r = 0; r < 4; ++r) {
        const float c = fast_tanh(y[r]);
        const float d = bf2f((unsigned short)(d4[nt] >> (16 * r)));
        const float h = hloc[nt][r];
        const float v = fmaf(d, c - h, h);
        hloc[nt][r] = v;
        o[r] = v;
      }
      __hip_atomic_store((unsigned long long*)(hout + (size_t)b * 1024 + j0[nt]),
                         pack4bf(o[0], o[1], o[2], o[3]),
                         __ATOMIC_RELAXED, __HIP_MEMORY_SCOPE_AGENT);
      *(f32x4*)(outp + (size_t)b * 1024 + j0[nt]) = o;
    }
    __syncthreads();                  // drains every thread's stores (vmcnt 0)
    if (tid == 0) atomicAdd(cnt, 1u);
    target += 8;
  }
}

// ---------------------------------------------------------------------------
extern "C" void kernel_launch(void* const* d_in, const int* in_sizes, int n_in,
                              void* d_out, int out_size, void* d_ws, size_t ws_size,
                              hipStream_t stream) {
  const float* x    = (const float*)d_in[0];
  const float* h0   = (const float*)d_in[1];
  const float* Wx   = (const float*)d_in[2];
  const float* R    = (const float*)d_in[3];
  const float* bias = (const float*)d_in[4];
  const float* Wd   = (const float*)d_in[5];
  const float* bd   = (const float*)d_in[6];
  float* out = (float*)d_out;

  // ws layout: [0,64MiB) delta bf16; [64MiB,+128KiB) hbuf (2x 32x1024 bf16);
  // counters at 64MiB+256KiB.
  unsigned short* delta_ws = (unsigned short*)d_ws;
  unsigned short* hbuf     = delta_ws + (size_t)32768 * 1024;
  unsigned int*   counters = (unsigned int*)((char*)d_ws + 64ull * 1024 * 1024 + 256 * 1024);

  hipMemsetAsync(counters, 0, 256, stream);

  dim3 pg(256, 16);
  proj_kernel<<<pg, 256, 0, stream>>>(x, Wx, Wd, bias, bd, out, delta_ws);
  rnn_kernel<<<16, 256, 0, stream>>>(R, h0, out, delta_ws, hbuf, counters);
}

// Round 3
// 7715.614 us; speedup vs baseline: 1.4731x; 1.4731x over previous
//
#include <hip/hip_runtime.h>
#include <stdint.h>

// T=1024, B=32, D=H=1024.  M = T*B = 32768.
typedef float  f32x4  __attribute__((ext_vector_type(4)));
typedef short  bf16x8 __attribute__((ext_vector_type(8)));

__device__ __forceinline__ unsigned short f2bf(float f) {
  union { float f; unsigned u; } v; v.f = f;
  unsigned r = v.u + 0x7fffu + ((v.u >> 16) & 1u);   // RNE, inputs are finite
  return (unsigned short)(r >> 16);
}
__device__ __forceinline__ float bf2f(unsigned short s) {
  union { unsigned u; float f; } v; v.u = ((unsigned)s) << 16; return v.f;
}
__device__ __forceinline__ bf16x8 pack8(float4 a, float4 b) {
  bf16x8 v;
  v[0]=(short)f2bf(a.x); v[1]=(short)f2bf(a.y); v[2]=(short)f2bf(a.z); v[3]=(short)f2bf(a.w);
  v[4]=(short)f2bf(b.x); v[5]=(short)f2bf(b.y); v[6]=(short)f2bf(b.z); v[7]=(short)f2bf(b.w);
  return v;
}
__device__ __forceinline__ unsigned long long pack4bf(float a, float b, float c, float d) {
  return (unsigned long long)f2bf(a) | ((unsigned long long)f2bf(b) << 16)
       | ((unsigned long long)f2bf(c) << 32) | ((unsigned long long)f2bf(d) << 48);
}
__device__ __forceinline__ f32x4 mfma16(bf16x8 a, bf16x8 b, f32x4 c) {
  return __builtin_amdgcn_mfma_f32_16x16x32_bf16(a, b, c, 0, 0, 0);
}
// fast tanh: 1 - 2/(exp(2y)+1); v_exp/v_rcp are ~1ulp, saturates correctly.
__device__ __forceinline__ float fast_tanh(float y) {
  return 1.0f - 2.0f * __builtin_amdgcn_rcpf(__expf(2.0f * y) + 1.0f);
}

// ---------------------------------------------------------------------------
// Phase 1 (unchanged, known-good): wx = x@Wx^T + bias -> d_out (fp32);
// delta = sigmoid(x@Wd^T + b_delta) -> ws (bf16).
// ---------------------------------------------------------------------------
__global__ __launch_bounds__(256) void proj_kernel(
    const float* __restrict__ x,  const float* __restrict__ Wx,
    const float* __restrict__ Wd, const float* __restrict__ bias,
    const float* __restrict__ bd, float* __restrict__ wx_out,
    unsigned short* __restrict__ delta_out)
{
  __shared__ __align__(16) unsigned short lA[128 * 40];
  __shared__ __align__(16) unsigned short lB[128 * 40];

  const int tid  = threadIdx.x;
  const int lane = tid & 63;
  const int wv   = tid >> 6;
  const int wm   = (wv >> 1) * 64;
  const int wn   = (wv & 1) * 64;
  const int l15  = lane & 15, lhi = lane >> 4;

  const int  bm    = blockIdx.x;
  const int  bn    = blockIdx.y;
  const bool isd   = bn >= 8;
  const float* W   = isd ? Wd : Wx;
  const int  ncol0 = (bn & 7) * 128;
  const int  row0  = bm * 128;

  const int srow = tid >> 1;
  const int scol = (tid & 1) * 16;

  f32x4 acc[4][4] = {};

  for (int k0 = 0; k0 < 1024; k0 += 32) {
    const float* pa = x + (size_t)(row0 + srow) * 1024 + (k0 + scol);
    const float* pb = W + (size_t)(ncol0 + srow) * 1024 + (k0 + scol);
    float4 a0 = *(const float4*)(pa + 0), a1 = *(const float4*)(pa + 4);
    float4 a2 = *(const float4*)(pa + 8), a3 = *(const float4*)(pa + 12);
    float4 b0 = *(const float4*)(pb + 0), b1 = *(const float4*)(pb + 4);
    float4 b2 = *(const float4*)(pb + 8), b3 = *(const float4*)(pb + 12);

    *(bf16x8*)&lA[srow * 40 + scol]     = pack8(a0, a1);
    *(bf16x8*)&lA[srow * 40 + scol + 8] = pack8(a2, a3);
    *(bf16x8*)&lB[srow * 40 + scol]     = pack8(b0, b1);
    *(bf16x8*)&lB[srow * 40 + scol + 8] = pack8(b2, b3);
    __syncthreads();

    bf16x8 af[4], bfr[4];
    #pragma unroll
    for (int i = 0; i < 4; ++i) {
      af[i]  = *(const bf16x8*)&lA[(wm + i * 16 + l15) * 40 + lhi * 8];
      bfr[i] = *(const bf16x8*)&lB[(wn + i * 16 + l15) * 40 + lhi * 8];
    }
    #pragma unroll
    for (int i = 0; i < 4; ++i)
      #pragma unroll
      for (int j = 0; j < 4; ++j)
        acc[i][j] = mfma16(af[i], bfr[j], acc[i][j]);
    __syncthreads();
  }

  #pragma unroll
  for (int i = 0; i < 4; ++i) {
    const int rbase = row0 + wm + i * 16 + lhi * 4;
    #pragma unroll
    for (int j = 0; j < 4; ++j) {
      const int col = ncol0 + wn + j * 16 + l15;
      #pragma unroll
      for (int r = 0; r < 4; ++r) {
        const size_t idx = (size_t)(rbase + r) * 1024 + col;
        const float v = acc[i][j][r];
        if (!isd) {
          wx_out[idx] = v + bias[col];
        } else {
          const float s = 1.0f / (1.0f + expf(-(v + bd[col])));
          delta_out[idx] = f2bf(s);
        }
      }
    }
  }
}

// ---------------------------------------------------------------------------
// Phase 2: persistent recurrence, single-latency coherent h exchange.
// grid = 16 WGs x 256 thr: blockIdx = bg*8 + chunk (bg = batch group of 16).
// y^T = R @ h^T: R = A-operand (reg/AGPR-resident ra[2][32]); h = B-operand
// staged per step: 256 threads x 128B contiguous asm global_load_dwordx4
// (sc0 sc1 = L1/L2-bypass, serviced coherently at L3), ONE vmcnt(0), then
// XOR-swizzled ds_write_b128 into a parity-double-buffered 32KB LDS tile;
// MFMA fragments come from ds_read_b128 (bank-uniform via the same XOR).
// Flag protocol: per-wave publish (2x8B agent atomic stores) -> wave-level
// s_waitcnt vmcnt(0) -> lane0 fetch_add(cnt). Consumer: ALL threads spin on
// cnt >= 32*(t+1). One __syncthreads per step (after ds_write). No fences.
// ---------------------------------------------------------------------------
__global__ __launch_bounds__(256, 1) void rnn_kernel(
    const float* __restrict__ R, const float* __restrict__ h0,
    float* __restrict__ out, const unsigned short* __restrict__ delta,
    unsigned short* __restrict__ hbuf, unsigned int* __restrict__ counters)
{
  __shared__ __align__(16) unsigned short hs[2][16384];   // 2 x 32KB

  const int tid  = threadIdx.x;
  const int lane = tid & 63;
  const int wv   = tid >> 6;
  const int l15  = lane & 15, lhi = lane >> 4;
  const int chunk = blockIdx.x & 7;
  const int bg    = blockIdx.x >> 3;
  const int B0    = bg * 16;
  const int cb    = chunk * 128 + wv * 32;
  unsigned int* cnt = counters + bg * 16;   // 64 B apart

  // R fragments as A-operand: ra[nt][kt] = R[j=cb+nt*16+l15][kt*32+lhi*8 ..+7]
  bf16x8 ra[2][32];
  #pragma unroll
  for (int nt = 0; nt < 2; ++nt) {
    const float* rrow = R + (size_t)(cb + nt * 16 + l15) * 1024 + lhi * 8;
    #pragma unroll
    for (int kt = 0; kt < 32; ++kt) {
      float4 u0 = *(const float4*)(rrow + kt * 32);
      float4 u1 = *(const float4*)(rrow + kt * 32 + 4);
      ra[nt][kt] = pack8(u0, u1);
    }
  }

  const int b = B0 + l15;                       // this lane's batch (C-col)
  const int j0[2] = { cb + lhi * 4, cb + 16 + lhi * 4 };

  // init h + publish into parity-0 buffer, per-wave flag add
  float hloc[2][4];
  #pragma unroll
  for (int nt = 0; nt < 2; ++nt) {
    const f32x4 hv = *(const f32x4*)(h0 + (size_t)b * 1024 + j0[nt]);
    hloc[nt][0] = hv[0]; hloc[nt][1] = hv[1];
    hloc[nt][2] = hv[2]; hloc[nt][3] = hv[3];
    __hip_atomic_store((unsigned long long*)(hbuf + (size_t)b * 1024 + j0[nt]),
                       pack4bf(hv[0], hv[1], hv[2], hv[3]),
                       __ATOMIC_RELAXED, __HIP_MEMORY_SCOPE_AGENT);
  }
  asm volatile("s_waitcnt vmcnt(0)" ::: "memory");
  if (lane == 0)
    __hip_atomic_fetch_add(cnt, 1u, __ATOMIC_RELAXED, __HIP_MEMORY_SCOPE_AGENT);

  // staging map: thread i -> row (i&15), 128B col-block (i>>4)
  const int lrow = tid & 15, cblk = tid >> 4;
  const size_t gstage = (size_t)(B0 + lrow) * 1024 + cblk * 64;   // halves
  int swz[8];
  #pragma unroll
  for (int m = 0; m < 8; ++m)
    swz[m] = lrow * 2048 + ((cblk * 128 + m * 16) ^ ((lrow & 7) << 4));

  // fragment-read base (bytes within LDS tile)
  const int rbase_l = l15 * 2048;
  const int rxor    = (l15 & 7) << 4;

  unsigned int target = 32;

  for (int t = 0; t < 1024; ++t) {
    const unsigned short* hin  = hbuf + (t & 1) * 32768;
    unsigned short*       hout = hbuf + ((t & 1) ^ 1) * 32768;
    float*                outp = out + (size_t)t * 32768;
    const unsigned short* dp   = delta + (size_t)t * 32768;

    // Prefetch wx / delta (plain loads; overlap with the spin).
    f32x4 wx4[2]; unsigned long long d4[2];
    #pragma unroll
    for (int nt = 0; nt < 2; ++nt) {
      wx4[nt] = *(const f32x4*)(outp + (size_t)b * 1024 + j0[nt]);
      d4[nt]  = *(const unsigned long long*)(dp + (size_t)b * 1024 + j0[nt]);
    }

    // Wait: all 32 waves of this batch group published h_t.
    while (__hip_atomic_load(cnt, __ATOMIC_RELAXED, __HIP_MEMORY_SCOPE_AGENT) < target) {}

    // Stage 128B of h: 8 back-to-back coherent loads, ONE latency.
    const unsigned short* gp = hin + gstage;
    f32x4 s0, s1, s2, s3, s4, s5, s6, s7;
    asm volatile(
      "global_load_dwordx4 %0, %8, off sc0 sc1\n\t"
      "global_load_dwordx4 %1, %8, off offset:16 sc0 sc1\n\t"
      "global_load_dwordx4 %2, %8, off offset:32 sc0 sc1\n\t"
      "global_load_dwordx4 %3, %8, off offset:48 sc0 sc1\n\t"
      "global_load_dwordx4 %4, %8, off offset:64 sc0 sc1\n\t"
      "global_load_dwordx4 %5, %8, off offset:80 sc0 sc1\n\t"
      "global_load_dwordx4 %6, %8, off offset:96 sc0 sc1\n\t"
      "global_load_dwordx4 %7, %8, off offset:112 sc0 sc1"
      : "=&v"(s0), "=&v"(s1), "=&v"(s2), "=&v"(s3),
        "=&v"(s4), "=&v"(s5), "=&v"(s6), "=&v"(s7)
      : "v"(gp)
      : "memory");
    asm volatile("s_waitcnt vmcnt(0)" ::: "memory");
    __builtin_amdgcn_sched_barrier(0);

    char* lb = (char*)&hs[t & 1][0];
    *(f32x4*)(lb + swz[0]) = s0;  *(f32x4*)(lb + swz[1]) = s1;
    *(f32x4*)(lb + swz[2]) = s2;  *(f32x4*)(lb + swz[3]) = s3;
    *(f32x4*)(lb + swz[4]) = s4;  *(f32x4*)(lb + swz[5]) = s5;
    *(f32x4*)(lb + swz[6]) = s6;  *(f32x4*)(lb + swz[7]) = s7;
    __syncthreads();

    // y^T = R_chunk @ h^T  (B-frags from LDS, 4-way acc rotation)
    const char* lr = lb + rbase_l;
    f32x4 acc[2][4] = {};
    #pragma unroll
    for (int kt = 0; kt < 32; ++kt) {
      const bf16x8 a = *(const bf16x8*)(lr + ((kt * 64 + lhi * 16) ^ rxor));
      acc[0][kt & 3] = mfma16(ra[0][kt], a, acc[0][kt & 3]);
      acc[1][kt & 3] = mfma16(ra[1][kt], a, acc[1][kt & 3]);
    }

    // blend + publish
    #pragma unroll
    for (int nt = 0; nt < 2; ++nt) {
      const f32x4 y = (acc[nt][0] + acc[nt][1]) + (acc[nt][2] + acc[nt][3]) + wx4[nt];
      f32x4 o;
      #pragma unroll
      for (int r = 0; r < 4; ++r) {
        const float c = fast_tanh(y[r]);
        const float d = bf2f((unsigned short)(d4[nt] >> (16 * r)));
        const float h = hloc[nt][r];
        const float v = fmaf(d, c - h, h);
        hloc[nt][r] = v;
        o[r] = v;
      }
      __hip_atomic_store((unsigned long long*)(hout + (size_t)b * 1024 + j0[nt]),
                         pack4bf(o[0], o[1], o[2], o[3]),
                         __ATOMIC_RELAXED, __HIP_MEMORY_SCOPE_AGENT);
      *(f32x4*)(outp + (size_t)b * 1024 + j0[nt]) = o;
    }
    asm volatile("s_waitcnt vmcnt(0)" ::: "memory");   // wave-level drain
    if (lane == 0)
      __hip_atomic_fetch_add(cnt, 1u, __ATOMIC_RELAXED, __HIP_MEMORY_SCOPE_AGENT);
    target += 32;
  }
}

// ---------------------------------------------------------------------------
extern "C" void kernel_launch(void* const* d_in, const int* in_sizes, int n_in,
                              void* d_out, int out_size, void* d_ws, size_t ws_size,
                              hipStream_t stream) {
  const float* x    = (const float*)d_in[0];
  const float* h0   = (const float*)d_in[1];
  const float* Wx   = (const float*)d_in[2];
  const float* R    = (const float*)d_in[3];
  const float* bias = (const float*)d_in[4];
  const float* Wd   = (const float*)d_in[5];
  const float* bd   = (const float*)d_in[6];
  float* out = (float*)d_out;

  // ws layout: [0,64MiB) delta bf16; [64MiB,+128KiB) hbuf (2x 32x1024 bf16);
  // counters at 64MiB+256KiB.
  unsigned short* delta_ws = (unsigned short*)d_ws;
  unsigned short* hbuf     = delta_ws + (size_t)32768 * 1024;
  unsigned int*   counters = (unsigned int*)((char*)d_ws + 64ull * 1024 * 1024 + 256 * 1024);

  hipMemsetAsync(counters, 0, 256, stream);

  dim3 pg(256, 16);
  proj_kernel<<<pg, 256, 0, stream>>>(x, Wx, Wd, bias, bd, out, delta_ws);
  rnn_kernel<<<16, 256, 0, stream>>>(R, h0, out, delta_ws, hbuf, counters);
}

// Round 4
// 5663.442 us; speedup vs baseline: 2.0069x; 1.3624x over previous
//
#include <hip/hip_runtime.h>
#include <stdint.h>

// T=1024, B=32, D=H=1024.  M = T*B = 32768.
typedef float  f32x4  __attribute__((ext_vector_type(4)));
typedef short  bf16x8 __attribute__((ext_vector_type(8)));
typedef unsigned int u32x4 __attribute__((ext_vector_type(4)));

__device__ __forceinline__ unsigned short f2bf(float f) {
  union { float f; unsigned u; } v; v.f = f;
  unsigned r = v.u + 0x7fffu + ((v.u >> 16) & 1u);   // RNE, inputs are finite
  return (unsigned short)(r >> 16);
}
__device__ __forceinline__ float bf2f(unsigned short s) {
  union { unsigned u; float f; } v; v.u = ((unsigned)s) << 16; return v.f;
}
__device__ __forceinline__ bf16x8 pack8(float4 a, float4 b) {
  bf16x8 v;
  v[0]=(short)f2bf(a.x); v[1]=(short)f2bf(a.y); v[2]=(short)f2bf(a.z); v[3]=(short)f2bf(a.w);
  v[4]=(short)f2bf(b.x); v[5]=(short)f2bf(b.y); v[6]=(short)f2bf(b.z); v[7]=(short)f2bf(b.w);
  return v;
}
__device__ __forceinline__ unsigned long long pack4bf(float a, float b, float c, float d) {
  return (unsigned long long)f2bf(a) | ((unsigned long long)f2bf(b) << 16)
       | ((unsigned long long)f2bf(c) << 32) | ((unsigned long long)f2bf(d) << 48);
}
__device__ __forceinline__ f32x4 mfma16(bf16x8 a, bf16x8 b, f32x4 c) {
  return __builtin_amdgcn_mfma_f32_16x16x32_bf16(a, b, c, 0, 0, 0);
}
// fast tanh: 1 - 2/(exp(2y)+1); v_exp/v_rcp are ~1ulp, saturates correctly.
__device__ __forceinline__ float fast_tanh(float y) {
  return 1.0f - 2.0f * __builtin_amdgcn_rcpf(__expf(2.0f * y) + 1.0f);
}

// ---------------------------------------------------------------------------
// Phase 1 (unchanged, known-good): wx = x@Wx^T + bias -> d_out (fp32);
// delta = sigmoid(x@Wd^T + b_delta) -> ws (bf16).
// ---------------------------------------------------------------------------
__global__ __launch_bounds__(256) void proj_kernel(
    const float* __restrict__ x,  const float* __restrict__ Wx,
    const float* __restrict__ Wd, const float* __restrict__ bias,
    const float* __restrict__ bd, float* __restrict__ wx_out,
    unsigned short* __restrict__ delta_out)
{
  __shared__ __align__(16) unsigned short lA[128 * 40];
  __shared__ __align__(16) unsigned short lB[128 * 40];

  const int tid  = threadIdx.x;
  const int lane = tid & 63;
  const int wv   = tid >> 6;
  const int wm   = (wv >> 1) * 64;
  const int wn   = (wv & 1) * 64;
  const int l15  = lane & 15, lhi = lane >> 4;

  const int  bm    = blockIdx.x;
  const int  bn    = blockIdx.y;
  const bool isd   = bn >= 8;
  const float* W   = isd ? Wd : Wx;
  const int  ncol0 = (bn & 7) * 128;
  const int  row0  = bm * 128;

  const int srow = tid >> 1;
  const int scol = (tid & 1) * 16;

  f32x4 acc[4][4] = {};

  for (int k0 = 0; k0 < 1024; k0 += 32) {
    const float* pa = x + (size_t)(row0 + srow) * 1024 + (k0 + scol);
    const float* pb = W + (size_t)(ncol0 + srow) * 1024 + (k0 + scol);
    float4 a0 = *(const float4*)(pa + 0), a1 = *(const float4*)(pa + 4);
    float4 a2 = *(const float4*)(pa + 8), a3 = *(const float4*)(pa + 12);
    float4 b0 = *(const float4*)(pb + 0), b1 = *(const float4*)(pb + 4);
    float4 b2 = *(const float4*)(pb + 8), b3 = *(const float4*)(pb + 12);

    *(bf16x8*)&lA[srow * 40 + scol]     = pack8(a0, a1);
    *(bf16x8*)&lA[srow * 40 + scol + 8] = pack8(a2, a3);
    *(bf16x8*)&lB[srow * 40 + scol]     = pack8(b0, b1);
    *(bf16x8*)&lB[srow * 40 + scol + 8] = pack8(b2, b3);
    __syncthreads();

    bf16x8 af[4], bfr[4];
    #pragma unroll
    for (int i = 0; i < 4; ++i) {
      af[i]  = *(const bf16x8*)&lA[(wm + i * 16 + l15) * 40 + lhi * 8];
      bfr[i] = *(const bf16x8*)&lB[(wn + i * 16 + l15) * 40 + lhi * 8];
    }
    #pragma unroll
    for (int i = 0; i < 4; ++i)
      #pragma unroll
      for (int j = 0; j < 4; ++j)
        acc[i][j] = mfma16(af[i], bfr[j], acc[i][j]);
    __syncthreads();
  }

  #pragma unroll
  for (int i = 0; i < 4; ++i) {
    const int rbase = row0 + wm + i * 16 + lhi * 4;
    #pragma unroll
    for (int j = 0; j < 4; ++j) {
      const int col = ncol0 + wn + j * 16 + l15;
      #pragma unroll
      for (int r = 0; r < 4; ++r) {
        const size_t idx = (size_t)(rbase + r) * 1024 + col;
        const float v = acc[i][j][r];
        if (!isd) {
          wx_out[idx] = v + bias[col];
        } else {
          const float s = 1.0f / (1.0f + expf(-(v + bd[col])));
          delta_out[idx] = f2bf(s);
        }
      }
    }
  }
}

// ---------------------------------------------------------------------------
// Phase 2: persistent recurrence, decontended per-wave flag protocol.
// grid = 16 WGs x 256 thr: blockIdx = bg*8 + chunk (bg = batch group of 16).
// y^T = R @ h^T: R = A-operand (reg/AGPR-resident ra[2][32]); h = B-operand
// staged per step via 256x128B coherent dwordx4 loads -> XOR-swizzled LDS.
// Flags: 32 u32 slots per bg (one 128B line). Producer wave: publish 2x8B
// agent stores -> wave vmcnt(0) -> lane0 plain coherent store slot=t+2.
// Consumer: EVERY wave polls the whole line (64 lanes same addr = 1 coalesced
// transaction) with 8x dwordx4 sc0 sc1 + min-reduce; self-releases, no extra
// barrier. Fat fp32 out-stores moved AFTER the flag store (off critical path).
// ---------------------------------------------------------------------------
__global__ __launch_bounds__(256, 1) void rnn_kernel(
    const float* __restrict__ R, const float* __restrict__ h0,
    float* __restrict__ out, const unsigned short* __restrict__ delta,
    unsigned short* __restrict__ hbuf, unsigned int* __restrict__ counters)
{
  __shared__ __align__(16) unsigned short hs[2][16384];   // 2 x 32KB

  const int tid  = threadIdx.x;
  const int lane = tid & 63;
  const int wv   = tid >> 6;
  const int l15  = lane & 15, lhi = lane >> 4;
  const int chunk = blockIdx.x & 7;
  const int bg    = blockIdx.x >> 3;
  const int B0    = bg * 16;
  const int cb    = chunk * 128 + wv * 32;
  unsigned int* flags = counters + bg * 32;     // 128B line per bg
  const int gwv = chunk * 4 + wv;               // this wave's slot (0..31)

  // R fragments as A-operand: ra[nt][kt] = R[j=cb+nt*16+l15][kt*32+lhi*8 ..+7]
  bf16x8 ra[2][32];
  #pragma unroll
  for (int nt = 0; nt < 2; ++nt) {
    const float* rrow = R + (size_t)(cb + nt * 16 + l15) * 1024 + lhi * 8;
    #pragma unroll
    for (int kt = 0; kt < 32; ++kt) {
      float4 u0 = *(const float4*)(rrow + kt * 32);
      float4 u1 = *(const float4*)(rrow + kt * 32 + 4);
      ra[nt][kt] = pack8(u0, u1);
    }
  }

  const int b = B0 + l15;                       // this lane's batch (C-col)
  const int j0[2] = { cb + lhi * 4, cb + 16 + lhi * 4 };

  // init h + publish into parity-0 buffer; per-wave flag = 1
  float hloc[2][4];
  #pragma unroll
  for (int nt = 0; nt < 2; ++nt) {
    const f32x4 hv = *(const f32x4*)(h0 + (size_t)b * 1024 + j0[nt]);
    hloc[nt][0] = hv[0]; hloc[nt][1] = hv[1];
    hloc[nt][2] = hv[2]; hloc[nt][3] = hv[3];
    __hip_atomic_store((unsigned long long*)(hbuf + (size_t)b * 1024 + j0[nt]),
                       pack4bf(hv[0], hv[1], hv[2], hv[3]),
                       __ATOMIC_RELAXED, __HIP_MEMORY_SCOPE_AGENT);
  }
  asm volatile("s_waitcnt vmcnt(0)" ::: "memory");
  if (lane == 0)
    __hip_atomic_store(&flags[gwv], 1u, __ATOMIC_RELAXED, __HIP_MEMORY_SCOPE_AGENT);

  // staging map: thread i -> row (i&15), 128B col-block (i>>4)
  const int lrow = tid & 15, cblk = tid >> 4;
  const size_t gstage = (size_t)(B0 + lrow) * 1024 + cblk * 64;   // halves
  int swz[8];
  #pragma unroll
  for (int m = 0; m < 8; ++m)
    swz[m] = lrow * 2048 + ((cblk * 128 + m * 16) ^ ((lrow & 7) << 4));

  // fragment-read base (bytes within LDS tile)
  const int rbase_l = l15 * 2048;
  const int rxor    = (l15 & 7) << 4;

  for (int t = 0; t < 1024; ++t) {
    const unsigned short* hin  = hbuf + (t & 1) * 32768;
    unsigned short*       hout = hbuf + ((t & 1) ^ 1) * 32768;
    float*                outp = out + (size_t)t * 32768;
    const unsigned short* dp   = delta + (size_t)t * 32768;
    const unsigned int target = (unsigned)t + 1u;

    // Prefetch wx / delta (plain loads; overlap with the poll below).
    f32x4 wx4[2]; unsigned long long d4[2];
    #pragma unroll
    for (int nt = 0; nt < 2; ++nt) {
      wx4[nt] = *(const f32x4*)(outp + (size_t)b * 1024 + j0[nt]);
      d4[nt]  = *(const unsigned long long*)(dp + (size_t)b * 1024 + j0[nt]);
    }

    // Poll: all 32 waves of this bg published h_t (slot >= t+1).
    // Wave-uniform address -> coalesced single transaction per load.
    for (;;) {
      u32x4 f0, f1, f2, f3, f4, f5, f6, f7;
      asm volatile(
        "global_load_dwordx4 %0, %8, off sc0 sc1\n\t"
        "global_load_dwordx4 %1, %8, off offset:16 sc0 sc1\n\t"
        "global_load_dwordx4 %2, %8, off offset:32 sc0 sc1\n\t"
        "global_load_dwordx4 %3, %8, off offset:48 sc0 sc1\n\t"
        "global_load_dwordx4 %4, %8, off offset:64 sc0 sc1\n\t"
        "global_load_dwordx4 %5, %8, off offset:80 sc0 sc1\n\t"
        "global_load_dwordx4 %6, %8, off offset:96 sc0 sc1\n\t"
        "global_load_dwordx4 %7, %8, off offset:112 sc0 sc1\n\t"
        "s_waitcnt vmcnt(0)"
        : "=&v"(f0), "=&v"(f1), "=&v"(f2), "=&v"(f3),
          "=&v"(f4), "=&v"(f5), "=&v"(f6), "=&v"(f7)
        : "v"(flags)
        : "memory");
      unsigned m = f0[0];
      #pragma unroll
      for (int q = 1; q < 4; ++q) m = m < f0[q] ? m : f0[q];
      #pragma unroll
      for (int q = 0; q < 4; ++q) { m = m < f1[q] ? m : f1[q]; m = m < f2[q] ? m : f2[q]; }
      #pragma unroll
      for (int q = 0; q < 4; ++q) { m = m < f3[q] ? m : f3[q]; m = m < f4[q] ? m : f4[q]; }
      #pragma unroll
      for (int q = 0; q < 4; ++q) { m = m < f5[q] ? m : f5[q]; m = m < f6[q] ? m : f6[q]; }
      #pragma unroll
      for (int q = 0; q < 4; ++q) m = m < f7[q] ? m : f7[q];
      if (m >= target) break;
    }

    // Stage 128B of h: 8 back-to-back coherent loads, ONE latency.
    const unsigned short* gp = hin + gstage;
    f32x4 s0, s1, s2, s3, s4, s5, s6, s7;
    asm volatile(
      "global_load_dwordx4 %0, %8, off sc0 sc1\n\t"
      "global_load_dwordx4 %1, %8, off offset:16 sc0 sc1\n\t"
      "global_load_dwordx4 %2, %8, off offset:32 sc0 sc1\n\t"
      "global_load_dwordx4 %3, %8, off offset:48 sc0 sc1\n\t"
      "global_load_dwordx4 %4, %8, off offset:64 sc0 sc1\n\t"
      "global_load_dwordx4 %5, %8, off offset:80 sc0 sc1\n\t"
      "global_load_dwordx4 %6, %8, off offset:96 sc0 sc1\n\t"
      "global_load_dwordx4 %7, %8, off offset:112 sc0 sc1"
      : "=&v"(s0), "=&v"(s1), "=&v"(s2), "=&v"(s3),
        "=&v"(s4), "=&v"(s5), "=&v"(s6), "=&v"(s7)
      : "v"(gp)
      : "memory");
    asm volatile("s_waitcnt vmcnt(0)" ::: "memory");
    __builtin_amdgcn_sched_barrier(0);

    char* lb = (char*)&hs[t & 1][0];
    *(f32x4*)(lb + swz[0]) = s0;  *(f32x4*)(lb + swz[1]) = s1;
    *(f32x4*)(lb + swz[2]) = s2;  *(f32x4*)(lb + swz[3]) = s3;
    *(f32x4*)(lb + swz[4]) = s4;  *(f32x4*)(lb + swz[5]) = s5;
    *(f32x4*)(lb + swz[6]) = s6;  *(f32x4*)(lb + swz[7]) = s7;
    __syncthreads();

    // y^T = R_chunk @ h^T  (B-frags from LDS, 4-way acc rotation)
    const char* lr = lb + rbase_l;
    f32x4 acc[2][4] = {};
    #pragma unroll
    for (int kt = 0; kt < 32; ++kt) {
      const bf16x8 a = *(const bf16x8*)(lr + ((kt * 64 + lhi * 16) ^ rxor));
      acc[0][kt & 3] = mfma16(ra[0][kt], a, acc[0][kt & 3]);
      acc[1][kt & 3] = mfma16(ra[1][kt], a, acc[1][kt & 3]);
    }

    // blend; publish h first, then flag, THEN the fat fp32 out stores.
    f32x4 o[2];
    #pragma unroll
    for (int nt = 0; nt < 2; ++nt) {
      const f32x4 y = (acc[nt][0] + acc[nt][1]) + (acc[nt][2] + acc[nt][3]) + wx4[nt];
      #pragma unroll
      for (int r = 0; r < 4; ++r) {
        const float c = fast_tanh(y[r]);
        const float d = bf2f((unsigned short)(d4[nt] >> (16 * r)));
        const float h = hloc[nt][r];
        const float v = fmaf(d, c - h, h);
        hloc[nt][r] = v;
        o[nt][r] = v;
      }
      __hip_atomic_store((unsigned long long*)(hout + (size_t)b * 1024 + j0[nt]),
                         pack4bf(o[nt][0], o[nt][1], o[nt][2], o[nt][3]),
                         __ATOMIC_RELAXED, __HIP_MEMORY_SCOPE_AGENT);
    }
    asm volatile("s_waitcnt vmcnt(0)" ::: "memory");   // wave-level drain
    if (lane == 0)
      __hip_atomic_store(&flags[gwv], (unsigned)t + 2u,
                         __ATOMIC_RELAXED, __HIP_MEMORY_SCOPE_AGENT);
    #pragma unroll
    for (int nt = 0; nt < 2; ++nt)
      *(f32x4*)(outp + (size_t)b * 1024 + j0[nt]) = o[nt];
  }
}

// ---------------------------------------------------------------------------
extern "C" void kernel_launch(void* const* d_in, const int* in_sizes, int n_in,
                              void* d_out, int out_size, void* d_ws, size_t ws_size,
                              hipStream_t stream) {
  const float* x    = (const float*)d_in[0];
  const float* h0   = (const float*)d_in[1];
  const float* Wx   = (const float*)d_in[2];
  const float* R    = (const float*)d_in[3];
  const float* bias = (const float*)d_in[4];
  const float* Wd   = (const float*)d_in[5];
  const float* bd   = (const float*)d_in[6];
  float* out = (float*)d_out;

  // ws layout: [0,64MiB) delta bf16; [64MiB,+128KiB) hbuf (2x 32x1024 bf16);
  // flags at 64MiB+256KiB (2 x 128B lines).
  unsigned short* delta_ws = (unsigned short*)d_ws;
  unsigned short* hbuf     = delta_ws + (size_t)32768 * 1024;
  unsigned int*   counters = (unsigned int*)((char*)d_ws + 64ull * 1024 * 1024 + 256 * 1024);

  hipMemsetAsync(counters, 0, 256, stream);

  dim3 pg(256, 16);
  proj_kernel<<<pg, 256, 0, stream>>>(x, Wx, Wd, bias, bd, out, delta_ws);
  rnn_kernel<<<16, 256, 0, stream>>>(R, h0, out, delta_ws, hbuf, counters);
}